// Round 5
// baseline (487.352 us; speedup 1.0000x reference)
//
#include <hip/hip_runtime.h>

#define DD 128
#define HH 160
#define WW 160
#define PLANE (DD * HH * WW)   // 3276800 voxels
#define HALF  (PLANE / 2)      // 1638400 — exact

// ---------------------------------------------------------------------------
// Pack: channel-major velocity -> interleaved xyz, prescaled by 2^-7 (exact).
// ---------------------------------------------------------------------------
__global__ __launch_bounds__(256) void pack_kernel(const float* __restrict__ vel,
                                                   float* __restrict__ out) {
    int idx = blockIdx.x * blockDim.x + threadIdx.x;
    if (idx >= PLANE) return;
    const float s = 1.0f / 128.0f;
    float vx = __fmul_rn(vel[idx],             s);
    float vy = __fmul_rn(vel[idx + PLANE],     s);
    float vz = __fmul_rn(vel[idx + 2 * PLANE], s);
    float* p = out + idx * 3;
    p[0] = vx; p[1] = vy; p[2] = vz;
}

// ---------------------------------------------------------------------------
// Phase 1: compute sample position, issue all 8 corner gathers (results land
// in cv[24], kept live until phase 2), compute masked weights.
// All fp math via _rn intrinsics in the reference's exact order (chaotic
// iteration => must bit-match numpy; w*mask is exact: 0 or w).
// ---------------------------------------------------------------------------
__device__ __forceinline__ void gather_phase(const float* __restrict__ fin, int idx,
                                             float* __restrict__ cv,   // [24]
                                             float* __restrict__ cw,   // [8]
                                             float& fx, float& fy, float& fz) {
    int x = idx % WW;
    int y = (idx / WW) % HH;
    int z = idx / (WW * HH);

    const float* self = fin + idx * 3;
    fx = self[0]; fy = self[1]; fz = self[2];

    float px = __fadd_rn((float)x, __fmul_rn(fx, 100.0f));
    float py = __fadd_rn((float)y, __fmul_rn(fy, 100.0f));
    float pz = __fadd_rn((float)z, __fmul_rn(fz, 100.0f));

    float gx = __fmul_rn(__fdiv_rn(__fsub_rn(px, 79.5f), 159.0f), 2.0f);
    float gy = __fmul_rn(__fdiv_rn(__fsub_rn(py, 79.5f), 159.0f), 2.0f);
    float gz = __fmul_rn(__fdiv_rn(__fsub_rn(pz, 63.5f), 127.0f), 2.0f);

    float ix = __fmul_rn(__fmul_rn(__fadd_rn(gx, 1.0f), 0.5f), 159.0f);
    float iy = __fmul_rn(__fmul_rn(__fadd_rn(gy, 1.0f), 0.5f), 159.0f);
    float iz = __fmul_rn(__fmul_rn(__fadd_rn(gz, 1.0f), 0.5f), 127.0f);

    float x0f = floorf(ix), y0f = floorf(iy), z0f = floorf(iz);
    int x0 = (int)x0f, y0 = (int)y0f, z0 = (int)z0f;

    int xc[2], yc[2], zc[2];
    bool xin[2], yin[2], zin[2];
#pragma unroll
    for (int d = 0; d < 2; ++d) {
        int xv = x0 + d, yv = y0 + d, zv = z0 + d;
        xin[d] = (xv >= 0) && (xv < WW);
        yin[d] = (yv >= 0) && (yv < HH);
        zin[d] = (zv >= 0) && (zv < DD);
        xc[d] = min(max(xv, 0), WW - 1);
        yc[d] = min(max(yv, 0), HH - 1);
        zc[d] = min(max(zv, 0), DD - 1);
    }

    // Issue all 8 corner loads back-to-back (consumed only in combine_phase).
#pragma unroll
    for (int dz = 0; dz < 2; ++dz) {
#pragma unroll
        for (int dy = 0; dy < 2; ++dy) {
#pragma unroll
            for (int dx = 0; dx < 2; ++dx) {
                int c = dz * 4 + dy * 2 + dx;
                const float* p = fin + ((zc[dz] * HH + yc[dy]) * WW + xc[dx]) * 3;
                cv[c * 3 + 0] = p[0];
                cv[c * 3 + 1] = p[1];
                cv[c * 3 + 2] = p[2];
            }
        }
    }

    // Weights (after the loads are issued — keeps them off the issue path).
    float wx1 = __fsub_rn(ix, x0f);
    float wy1 = __fsub_rn(iy, y0f);
    float wz1 = __fsub_rn(iz, z0f);
    float wxa[2] = { __fsub_rn(1.0f, wx1), wx1 };
    float wya[2] = { __fsub_rn(1.0f, wy1), wy1 };
    float wza[2] = { __fsub_rn(1.0f, wz1), wz1 };
#pragma unroll
    for (int dz = 0; dz < 2; ++dz)
#pragma unroll
        for (int dy = 0; dy < 2; ++dy)
#pragma unroll
            for (int dx = 0; dx < 2; ++dx) {
                int c = dz * 4 + dy * 2 + dx;
                float w = __fmul_rn(__fmul_rn(wza[dz], wya[dy]), wxa[dx]);
                cw[c] = (zin[dz] && yin[dy] && xin[dx]) ? w : 0.0f;
            }
}

__device__ __forceinline__ void combine_phase(const float* __restrict__ cv,
                                              const float* __restrict__ cw,
                                              float fx, float fy, float fz,
                                              float& ox, float& oy, float& oz) {
    float sx = 0.0f, sy = 0.0f, sz = 0.0f;
#pragma unroll
    for (int c = 0; c < 8; ++c) {   // reference corner order: z outer, y, x
        sx = __fadd_rn(sx, __fmul_rn(cv[c * 3 + 0], cw[c]));
        sy = __fadd_rn(sy, __fmul_rn(cv[c * 3 + 1], cw[c]));
        sz = __fadd_rn(sz, __fmul_rn(cv[c * 3 + 2], cw[c]));
    }
    ox = __fadd_rn(fx, sx);
    oy = __fadd_rn(fy, sy);
    oz = __fadd_rn(fz, sz);
}

// ---------------------------------------------------------------------------
// One step, TWO independent voxels per thread (idx, idx+HALF): both gather
// batches are issued before either is consumed -> ~16 gathers in flight/wave.
// DST_CM: final step writes channel-major into d_out.
// ---------------------------------------------------------------------------
template<bool DST_CM>
__global__ __launch_bounds__(256) void diffeo_step(const float* __restrict__ fin,
                                                   float* __restrict__ fout) {
    int t = blockIdx.x * blockDim.x + threadIdx.x;
    if (t >= HALF) return;
    int idxA = t;
    int idxB = t + HALF;

    float cvA[24], cwA[8], fxA, fyA, fzA;
    float cvB[24], cwB[8], fxB, fyB, fzB;

    gather_phase(fin, idxA, cvA, cwA, fxA, fyA, fzA);
    gather_phase(fin, idxB, cvB, cwB, fxB, fyB, fzB);

    float oxA, oyA, ozA, oxB, oyB, ozB;
    combine_phase(cvA, cwA, fxA, fyA, fzA, oxA, oyA, ozA);
    combine_phase(cvB, cwB, fxB, fyB, fzB, oxB, oyB, ozB);

    if (DST_CM) {
        fout[idxA]             = oxA;
        fout[idxA + PLANE]     = oyA;
        fout[idxA + 2 * PLANE] = ozA;
        fout[idxB]             = oxB;
        fout[idxB + PLANE]     = oyB;
        fout[idxB + 2 * PLANE] = ozB;
    } else {
        float* pA = fout + idxA * 3;
        pA[0] = oxA; pA[1] = oyA; pA[2] = ozA;
        float* pB = fout + idxB * 3;
        pB[0] = oxB; pB[1] = oyB; pB[2] = ozB;
    }
}

extern "C" void kernel_launch(void* const* d_in, const int* in_sizes, int n_in,
                              void* d_out, int out_size, void* d_ws, size_t ws_size,
                              hipStream_t stream) {
    const float* velocity = (const float*)d_in[0];
    float* A = (float*)d_out;  // interleaved scratch until the final step
    float* B = (float*)d_ws;   // interleaved scratch

    const int threads = 256;
    const int pack_blocks = (PLANE + threads - 1) / threads;
    const int step_blocks = (HALF + threads - 1) / threads;

    pack_kernel<<<pack_blocks, threads, 0, stream>>>(velocity, B);

    // s1..s7 ping-pong; s7 reads B, writes d_out channel-major. Never aliased.
    diffeo_step<false><<<step_blocks, threads, 0, stream>>>(B, A);  // s1
    diffeo_step<false><<<step_blocks, threads, 0, stream>>>(A, B);  // s2
    diffeo_step<false><<<step_blocks, threads, 0, stream>>>(B, A);  // s3
    diffeo_step<false><<<step_blocks, threads, 0, stream>>>(A, B);  // s4
    diffeo_step<false><<<step_blocks, threads, 0, stream>>>(B, A);  // s5
    diffeo_step<false><<<step_blocks, threads, 0, stream>>>(A, B);  // s6
    diffeo_step<true ><<<step_blocks, threads, 0, stream>>>(B, A);  // s7 -> d_out
}